// Round 4
// baseline (102.120 us; speedup 1.0000x reference)
//
#include <hip/hip_runtime.h>
#include <math.h>

#define B_   2
#define S_   16384
#define SK_  1024
#define IMW_ 128
#define EPS_ 1e-5f

typedef __attribute__((ext_vector_type(8))) short short8v;
typedef __attribute__((ext_vector_type(4))) short short4v;
typedef __attribute__((ext_vector_type(4))) float f32x4;

__device__ __forceinline__ ushort f2bfu(float x) {
    uint u = __float_as_uint(x);
    u += 0x7fffu + ((u >> 16) & 1u);   // RNE
    return (ushort)(u >> 16);
}
__device__ __forceinline__ uint cvtpk(float a, float b) {  // [bf16(a) | bf16(b)<<16]
    uint r;
    asm("v_cvt_pk_bf16_f32 %0, %1, %2" : "=v"(r) : "v"(a), "v"(b));
    return r;
}
__device__ __forceinline__ short8v pack8(float4 a, float4 b) {
    union { uint4 u; short8v s; } c;
    c.u = make_uint4(cvtpk(a.x, a.y), cvtpk(a.z, a.w), cvtpk(b.x, b.y), cvtpk(b.z, b.w));
    return c.s;
}

// ---------------------------------------------------------------- prep: Wsr -> Wsrb[co][tap*128+ci] bf16
__global__ __launch_bounds__(256) void k_prep(const float* __restrict__ Wsr,
                                              ushort* __restrict__ Wsrb) {
    int i = blockIdx.x * 2048 + threadIdx.x * 8;   // 128 blocks
    int co = i >> 11, tap = (i >> 7) & 15, ci = i & 127;
    float v[8];
    #pragma unroll
    for (int j = 0; j < 8; ++j) v[j] = Wsr[((co * 128 + ci + j) * 16) + tap];
    *(uint4*)(Wsrb + i) = make_uint4(cvtpk(v[0], v[1]), cvtpk(v[2], v[3]),
                                     cvtpk(v[4], v[5]), cvtpk(v[6], v[7]));
}

// ---------------------------------------------------------------- fused conv + LN + K/V GEMM + RoPE
// 128 blocks (2 b x 64 rowblk), 256 thr. Block owns 16 patch rows.
__global__ __launch_bounds__(256) void k_kv(
    const float* __restrict__ hid, const ushort* __restrict__ Wsrb,
    const float* __restrict__ Wk, const float* __restrict__ Wv,
    const float* __restrict__ fc, const float* __restrict__ bsr,
    const float* __restrict__ lng, const float* __restrict__ lnb,
    const float* __restrict__ bk, const float* __restrict__ bv,
    ushort* __restrict__ Kb, ushort* __restrict__ VTb)
{
    __shared__ ushort sP[2][16][512];   // patch bf16, k-XOR-swizzled, dbuf (32 KB)
    __shared__ float  sX[16][132];      // conv out fp32 (+b_sr)
    __shared__ ushort sXb[16][128];     // LN out bf16, swizzled
    __shared__ float  sFR[16][32];
    __shared__ float  sFI[16][32];

    const int t = threadIdx.x;
    const int lane = t & 63, w = t >> 6;
    const int g = lane >> 4, ln = lane & 15;
    const int b = blockIdx.x >> 6;
    const int pos0 = (blockIdx.x & 63) * 16;

    // ---- freq 4x4 means for this block's 16 positions
    #pragma unroll
    for (int i = 0; i < 2; ++i) {
        int pid = t + 256 * i;                 // 512 = 16 pos * 32 c
        int p = pid >> 5, c = pid & 31;
        int pg = pos0 + p;
        int y = pg >> 5, x = pg & 31;
        float sr = 0.f, si = 0.f;
        #pragma unroll
        for (int i1 = 0; i1 < 4; ++i1)
            #pragma unroll
            for (int i3 = 0; i3 < 4; ++i3) {
                int s = (4 * y + i1) * IMW_ + 4 * x + i3;
                sr += fc[s * 64 + 2 * c];
                si += fc[s * 64 + 2 * c + 1];
            }
        sFR[p][c] = sr * 0.0625f;
        sFI[p][c] = si * 0.0625f;
    }

    // ---- conv: out[16 pos][128 ch], K = 2048 (tap-major), BK = 512, dbuf
    auto stage = [&](int chunk, int buf) {
        #pragma unroll
        for (int i = 0; i < 8; ++i) {
            int f = t + i * 256;               // 2048 float4 slots
            int p = f >> 7, tap = (f >> 5) & 3, c4 = f & 31;
            int pg = pos0 + p;
            int py = pg >> 5, px = pg & 31;
            int tg = chunk * 4 + tap;
            int s = (4 * py + (tg >> 2)) * IMW_ + 4 * px + (tg & 3);
            float4 v = *(const float4*)(hid + ((size_t)b * S_ + s) * 128 + c4 * 4);
            int k = (tap * 128 + c4 * 4) ^ ((p & 7) << 3);
            *(uint2*)(&sP[buf][p][k]) = make_uint2(cvtpk(v.x, v.y), cvtpk(v.z, v.w));
        }
    };

    f32x4 acc[2];
    #pragma unroll
    for (int m = 0; m < 2; ++m)
        #pragma unroll
        for (int r = 0; r < 4; ++r) acc[m][r] = 0.f;

    stage(0, 0);
    int buf = 0;
    for (int chunk = 0; chunk < 4; ++chunk) {
        __syncthreads();
        if (chunk < 3) stage(chunk + 1, buf ^ 1);
        #pragma unroll
        for (int ksl = 0; ksl < 16; ++ksl) {
            int kg = chunk * 512 + ksl * 32;
            short8v xf = *(const short8v*)&sP[buf][ln][(ksl * 32 + 8 * g) ^ ((ln & 7) << 3)];
            #pragma unroll
            for (int m = 0; m < 2; ++m) {
                short8v wf = *(const short8v*)(Wsrb + (size_t)(32 * w + 16 * m + ln) * 2048 + kg + 8 * g);
                acc[m] = __builtin_amdgcn_mfma_f32_16x16x32_bf16(wf, xf, acc[m], 0, 0, 0);
            }
        }
        buf ^= 1;
    }

    // D: (c = 32w+16m+4g+r, pos = ln) -> sX with b_sr
    #pragma unroll
    for (int m = 0; m < 2; ++m) {
        int c0 = 32 * w + 16 * m + 4 * g;
        float4 bs = *(const float4*)(bsr + c0);
        *(float4*)&sX[ln][c0] = make_float4(acc[m][0] + bs.x, acc[m][1] + bs.y,
                                            acc[m][2] + bs.z, acc[m][3] + bs.w);
    }
    __syncthreads();

    // ---- LN: row = t>>4, 16 threads per row
    {
        const int row = t >> 4, j0 = (t & 15) * 8;
        float4 a = *(const float4*)&sX[row][j0];
        float4 c = *(const float4*)&sX[row][j0 + 4];
        float s = a.x + a.y + a.z + a.w + c.x + c.y + c.z + c.w;
        #pragma unroll
        for (int m = 1; m < 16; m <<= 1) s += __shfl_xor(s, m, 64);
        float mu = s * (1.0f / 128.0f);
        float d[8] = {a.x - mu, a.y - mu, a.z - mu, a.w - mu,
                      c.x - mu, c.y - mu, c.z - mu, c.w - mu};
        float vs = 0.f;
        #pragma unroll
        for (int j = 0; j < 8; ++j) vs += d[j] * d[j];
        #pragma unroll
        for (int m = 1; m < 16; m <<= 1) vs += __shfl_xor(vs, m, 64);
        float rstd = rsqrtf(vs * (1.0f / 128.0f) + EPS_);
        float4 g0 = *(const float4*)(lng + j0);
        float4 g1 = *(const float4*)(lng + j0 + 4);
        float4 b0 = *(const float4*)(lnb + j0);
        float4 b1 = *(const float4*)(lnb + j0 + 4);
        float o[8];
        o[0] = d[0] * rstd * g0.x + b0.x; o[1] = d[1] * rstd * g0.y + b0.y;
        o[2] = d[2] * rstd * g0.z + b0.z; o[3] = d[3] * rstd * g0.w + b0.w;
        o[4] = d[4] * rstd * g1.x + b1.x; o[5] = d[5] * rstd * g1.y + b1.y;
        o[6] = d[6] * rstd * g1.z + b1.z; o[7] = d[7] * rstd * g1.w + b1.w;
        *(uint4*)&sXb[row][j0 ^ ((row & 7) << 3)] =
            make_uint4(cvtpk(o[0], o[1]), cvtpk(o[2], o[3]),
                       cvtpk(o[4], o[5]), cvtpk(o[6], o[7]));
    }
    __syncthreads();

    // ---- K/V GEMM: waves 0,1 -> K (h=0,1); waves 2,3 -> V (h=0,1)
    short8v xn[4];
    #pragma unroll
    for (int ks = 0; ks < 4; ++ks)
        xn[ks] = *(const short8v*)&sXb[ln][(32 * ks + 8 * g) ^ ((ln & 7) << 3)];

    const int h = w & 1;
    const float* W = (w < 2) ? Wk : Wv;
    f32x4 acc2[4];
    #pragma unroll
    for (int mt = 0; mt < 4; ++mt)
        #pragma unroll
        for (int r = 0; r < 4; ++r) acc2[mt][r] = 0.f;
    #pragma unroll
    for (int mt = 0; mt < 4; ++mt)
        #pragma unroll
        for (int ks = 0; ks < 4; ++ks) {
            const float* wp = W + (size_t)(64 * h + 16 * mt + ln) * 128 + 32 * ks + 8 * g;
            short8v wf = pack8(*(const float4*)wp, *(const float4*)(wp + 4));
            acc2[mt] = __builtin_amdgcn_mfma_f32_16x16x32_bf16(wf, xn[ks], acc2[mt], 0, 0, 0);
        }

    const int posg = pos0 + ln;
    const int bh = b * 2 + h;
    if (w < 2) {       // K: bias + RoPE(freq means) -> Kb[bh][pos][64]
        #pragma unroll
        for (int mt = 0; mt < 4; ++mt) {
            int col0 = 16 * mt + 4 * g;
            float4 bkv = *(const float4*)(bk + 64 * h + col0);
            float a0 = acc2[mt][0] + bkv.x, a1 = acc2[mt][1] + bkv.y;
            float a2 = acc2[mt][2] + bkv.z, a3 = acc2[mt][3] + bkv.w;
            float2 frv = *(const float2*)&sFR[ln][col0 >> 1];
            float2 fiv = *(const float2*)&sFI[ln][col0 >> 1];
            float o0 = a0 * frv.x - a1 * fiv.x;
            float o1 = a0 * fiv.x + a1 * frv.x;
            float o2 = a2 * frv.y - a3 * fiv.y;
            float o3 = a2 * fiv.y + a3 * frv.y;
            *(uint2*)(Kb + ((size_t)bh * SK_ + posg) * 64 + col0) =
                make_uint2(cvtpk(o0, o1), cvtpk(o2, o3));
        }
    } else {           // V: bias -> VTb[bh][d][pos] (transposed)
        #pragma unroll
        for (int mt = 0; mt < 4; ++mt) {
            int col0 = 16 * mt + 4 * g;
            float4 bvv = *(const float4*)(bv + 64 * h + col0);
            #pragma unroll
            for (int r = 0; r < 4; ++r)
                VTb[((size_t)bh * 64 + col0 + r) * SK_ + posg] =
                    f2bfu(acc2[mt][r] + (&bvv.x)[r]);
        }
    }
}

// ---------------------------------------------------------------- flash attention + fused Q-GEMM/RoPE
// 512 blocks (4 bh x 128 qtiles), 256 thr / 4 waves; wave owns 32 q rows.
__global__ __launch_bounds__(256) void k_attn(
    const float* __restrict__ hid, const float* __restrict__ Wq,
    const float* __restrict__ bq, const float* __restrict__ fc,
    const ushort* __restrict__ Kb, const ushort* __restrict__ VTb,
    float* __restrict__ out)
{
    __shared__ ushort sQ[128][64];   // head-local Q bf16, swizzled (16 KB)
    __shared__ ushort sK[64][72];
    __shared__ ushort sVT[64][72];
    const int t = threadIdx.x;
    const int lane = t & 63;
    const int w = t >> 6;
    const int g = lane >> 4, ln = lane & 15;
    const int bh = blockIdx.x >> 7;
    const int q0w = (blockIdx.x & 127) * 128 + w * 32;
    const int b = bh >> 1, h = bh & 1;

    // ---- Q-GEMM (this head's 64 channels only) + RoPE -> sQ (wave-private rows)
    {
        f32x4 qa[2][4];
        #pragma unroll
        for (int qt = 0; qt < 2; ++qt)
            #pragma unroll
            for (int mt = 0; mt < 4; ++mt)
                #pragma unroll
                for (int r = 0; r < 4; ++r) qa[qt][mt][r] = 0.f;

        #pragma unroll
        for (int ks = 0; ks < 4; ++ks) {
            short8v xf[2];
            #pragma unroll
            for (int qt = 0; qt < 2; ++qt) {
                const float* hp = hid + ((size_t)b * S_ + q0w + 16 * qt + ln) * 128 + 32 * ks + 8 * g;
                xf[qt] = pack8(*(const float4*)hp, *(const float4*)(hp + 4));
            }
            #pragma unroll
            for (int mt = 0; mt < 4; ++mt) {
                const float* wp = Wq + (size_t)(64 * h + 16 * mt + ln) * 128 + 32 * ks + 8 * g;
                short8v wf = pack8(*(const float4*)wp, *(const float4*)(wp + 4));
                qa[0][mt] = __builtin_amdgcn_mfma_f32_16x16x32_bf16(wf, xf[0], qa[0][mt], 0, 0, 0);
                qa[1][mt] = __builtin_amdgcn_mfma_f32_16x16x32_bf16(wf, xf[1], qa[1][mt], 0, 0, 0);
            }
        }
        const float scale = 0.18033688011112042f;   // 0.125 * log2(e)
        #pragma unroll
        for (int qt = 0; qt < 2; ++qt) {
            int pos = q0w + 16 * qt + ln;
            #pragma unroll
            for (int mt = 0; mt < 4; ++mt) {
                int col0 = 16 * mt + 4 * g;          // head-local channel base
                float4 fv = *(const float4*)(fc + (size_t)pos * 64 + col0);
                float4 bqv = *(const float4*)(bq + 64 * h + col0);
                float a0 = qa[qt][mt][0] + bqv.x, a1 = qa[qt][mt][1] + bqv.y;
                float a2 = qa[qt][mt][2] + bqv.z, a3 = qa[qt][mt][3] + bqv.w;
                float o0 = (a0 * fv.x - a1 * fv.y) * scale;
                float o1 = (a0 * fv.y + a1 * fv.x) * scale;
                float o2 = (a2 * fv.z - a3 * fv.w) * scale;
                float o3 = (a2 * fv.w + a3 * fv.z) * scale;
                int qrow = w * 32 + 16 * qt + ln;
                *(uint2*)&sQ[qrow][col0 ^ ((ln & 7) << 3)] =
                    make_uint2(cvtpk(o0, o1), cvtpk(o2, o3));
            }
        }
    }

    // reload as B-frags (wave-private rows: no barrier needed)
    short8v qf[2][2];
    #pragma unroll
    for (int qt = 0; qt < 2; ++qt)
        #pragma unroll
        for (int ks = 0; ks < 2; ++ks)
            qf[qt][ks] = *(const short8v*)&sQ[w * 32 + 16 * qt + ln][(32 * ks + 8 * g) ^ ((ln & 7) << 3)];

    f32x4 ctx[2][4];
    #pragma unroll
    for (int qt = 0; qt < 2; ++qt)
        #pragma unroll
        for (int dt = 0; dt < 4; ++dt)
            #pragma unroll
            for (int r = 0; r < 4; ++r) ctx[qt][dt][r] = 0.f;
    float m_run[2] = {-3.0e38f, -3.0e38f};
    float l_run[2] = {0.f, 0.f};

    const int sr = t >> 2, scol = (t & 3) * 16;
    const ushort* kgBase = Kb  + ((size_t)bh * SK_ + sr) * 64 + scol;
    const ushort* vgBase = VTb + ((size_t)bh * 64 + sr) * SK_ + scol;

    {   // prologue: chunk 0
        uint4 k0 = *(const uint4*)(kgBase);
        uint4 k1 = *(const uint4*)(kgBase + 8);
        uint4 v0 = *(const uint4*)(vgBase);
        uint4 v1 = *(const uint4*)(vgBase + 8);
        *(uint4*)&sK[sr][scol]      = k0;
        *(uint4*)&sK[sr][scol + 8]  = k1;
        *(uint4*)&sVT[sr][scol]     = v0;
        *(uint4*)&sVT[sr][scol + 8] = v1;
    }
    __syncthreads();

    uint4 kr0, kr1, vr0, vr1;
    for (int ch = 0; ch < 16; ++ch) {
        if (ch < 15) {
            const ushort* kg = kgBase + (size_t)(ch + 1) * 64 * 64;
            const ushort* vg = vgBase + (ch + 1) * 64;
            kr0 = *(const uint4*)(kg);
            kr1 = *(const uint4*)(kg + 8);
            vr0 = *(const uint4*)(vg);
            vr1 = *(const uint4*)(vg + 8);
        }

        f32x4 sc[4][2];
        #pragma unroll
        for (int kvt = 0; kvt < 4; ++kvt)
            #pragma unroll
            for (int qt = 0; qt < 2; ++qt)
                #pragma unroll
                for (int r = 0; r < 4; ++r) sc[kvt][qt][r] = 0.f;
        #pragma unroll
        for (int ks = 0; ks < 2; ++ks)
            #pragma unroll
            for (int kvt = 0; kvt < 4; ++kvt) {
                short8v kf = *(const short8v*)&sK[16 * kvt + ln][32 * ks + 8 * g];
                sc[kvt][0] = __builtin_amdgcn_mfma_f32_16x16x32_bf16(kf, qf[0][ks], sc[kvt][0], 0, 0, 0);
                sc[kvt][1] = __builtin_amdgcn_mfma_f32_16x16x32_bf16(kf, qf[1][ks], sc[kvt][1], 0, 0, 0);
            }

        #pragma unroll
        for (int qt = 0; qt < 2; ++qt) {
            float mx = sc[0][qt][0];
            #pragma unroll
            for (int kvt = 0; kvt < 4; ++kvt)
                #pragma unroll
                for (int r = 0; r < 4; ++r) mx = fmaxf(mx, sc[kvt][qt][r]);
            mx = fmaxf(mx, __shfl_xor(mx, 16, 64));
            mx = fmaxf(mx, __shfl_xor(mx, 32, 64));
            if (!__all(mx <= m_run[qt] + 8.0f)) {
                float mN  = fmaxf(m_run[qt], mx);
                float fac = __builtin_amdgcn_exp2f(m_run[qt] - mN);
                m_run[qt] = mN;
                l_run[qt] *= fac;
                #pragma unroll
                for (int r = 0; r < 4; ++r) {
                    float fbc = __shfl(fac, 4 * g + r, 64);
                    #pragma unroll
                    for (int dt = 0; dt < 4; ++dt) ctx[qt][dt][r] *= fbc;
                }
            }
            float ps = 0.f;
            #pragma unroll
            for (int kvt = 0; kvt < 4; ++kvt)
                #pragma unroll
                for (int r = 0; r < 4; ++r) {
                    float ev = __builtin_amdgcn_exp2f(sc[kvt][qt][r] - m_run[qt]);
                    sc[kvt][qt][r] = ev;
                    ps += ev;
                }
            ps += __shfl_xor(ps, 16, 64);
            ps += __shfl_xor(ps, 32, 64);
            l_run[qt] += ps;
        }

        #pragma unroll
        for (int ks2 = 0; ks2 < 2; ++ks2) {
            union { uint4 u; short8v s; } pf[2];
            #pragma unroll
            for (int qt = 0; qt < 2; ++qt) {
                pf[qt].u.x = cvtpk(sc[2 * ks2][qt][0],     sc[2 * ks2][qt][1]);
                pf[qt].u.y = cvtpk(sc[2 * ks2][qt][2],     sc[2 * ks2][qt][3]);
                pf[qt].u.z = cvtpk(sc[2 * ks2 + 1][qt][0], sc[2 * ks2 + 1][qt][1]);
                pf[qt].u.w = cvtpk(sc[2 * ks2 + 1][qt][2], sc[2 * ks2 + 1][qt][3]);
            }
            #pragma unroll
            for (int dt = 0; dt < 4; ++dt) {
                const int dd = 16 * dt + ln;
                short4v va = *(const short4v*)&sVT[dd][32 * ks2 + 4 * g];
                short4v vb = *(const short4v*)&sVT[dd][32 * ks2 + 16 + 4 * g];
                short8v vf = __builtin_shufflevector(va, vb, 0, 1, 2, 3, 4, 5, 6, 7);
                ctx[0][dt] = __builtin_amdgcn_mfma_f32_16x16x32_bf16(pf[0].s, vf, ctx[0][dt], 0, 0, 0);
                ctx[1][dt] = __builtin_amdgcn_mfma_f32_16x16x32_bf16(pf[1].s, vf, ctx[1][dt], 0, 0, 0);
            }
        }

        __syncthreads();
        if (ch < 15) {
            *(uint4*)&sK[sr][scol]      = kr0;
            *(uint4*)&sK[sr][scol + 8]  = kr1;
            *(uint4*)&sVT[sr][scol]     = vr0;
            *(uint4*)&sVT[sr][scol + 8] = vr1;
        }
        __syncthreads();
    }

    #pragma unroll
    for (int qt = 0; qt < 2; ++qt) {
        float inv = 1.0f / l_run[qt];
        #pragma unroll
        for (int r = 0; r < 4; ++r) {
            float ir = __shfl(inv, 4 * g + r, 64);
            int q = q0w + 16 * qt + 4 * g + r;
            float* dst = out + ((size_t)b * S_ + q) * 128 + h * 64;
            #pragma unroll
            for (int dt = 0; dt < 4; ++dt)
                dst[16 * dt + ln] = ctx[qt][dt][r] * ir;
        }
    }
}

// ---------------------------------------------------------------- launch
extern "C" void kernel_launch(void* const* d_in, const int* in_sizes, int n_in,
                              void* d_out, int out_size, void* d_ws, size_t ws_size,
                              hipStream_t stream) {
    const float* hid = (const float*)d_in[0];
    const float* fc  = (const float*)d_in[1];
    const float* Wq  = (const float*)d_in[2];
    const float* bq  = (const float*)d_in[3];
    const float* Wk  = (const float*)d_in[4];
    const float* bk  = (const float*)d_in[5];
    const float* Wv  = (const float*)d_in[6];
    const float* bv  = (const float*)d_in[7];
    const float* Wsr = (const float*)d_in[8];
    const float* bsr = (const float*)d_in[9];
    const float* lng = (const float*)d_in[10];
    const float* lnb = (const float*)d_in[11];
    float* out = (float*)d_out;

    ushort* ws   = (ushort*)d_ws;
    ushort* Wsrb = ws;                  // 262,144 ushort
    ushort* Kb   = ws + 262144;         // 262,144 ushort
    ushort* VTb  = ws + 524288;         // 262,144 ushort

    k_prep<<<128, 256, 0, stream>>>(Wsr, Wsrb);
    k_kv<<<128, 256, 0, stream>>>(hid, Wsrb, Wk, Wv, fc, bsr, lng, lnb, bk, bv, Kb, VTb);
    k_attn<<<512, 256, 0, stream>>>(hid, Wq, bq, fc, Kb, VTb, out);
}